// Round 1
// baseline (82.853 us; speedup 1.0000x reference)
//
#include <hip/hip_runtime.h>
#include <math.h>

#define NRAYS 32768      // 16*64*32
#define NSPH  1024
#define NCHUNK 4
#define CHUNK 256
#define RAYS_PER_BLOCK 64

__global__ __launch_bounds__(256) void sphere_kernel(
    const float* __restrict__ rays,
    const float* __restrict__ centers,
    const float* __restrict__ radii,
    float* __restrict__ out)
{
#pragma clang fp contract(off)
    __shared__ float cx[NSPH], cy[NSPH], cz[NSPH], r2[NSPH];
    __shared__ float s_min[NCHUNK][RAYS_PER_BLOCK];
    __shared__ int   s_arg[NCHUNK][RAYS_PER_BLOCK];
    __shared__ unsigned char s_val[NCHUNK][RAYS_PER_BLOCK];

    const int tid = threadIdx.x;

    // Stage all spheres into LDS (SoA). 16 KB.
    for (int i = tid; i < NSPH; i += 256) {
        cx[i] = centers[3*i + 0];
        cy[i] = centers[3*i + 1];
        cz[i] = centers[3*i + 2];
        float r = radii[i];
        r2[i] = r * r;
    }
    __syncthreads();

    const int lane  = tid & 63;   // ray within block
    const int chunk = tid >> 6;   // which 256-sphere chunk this thread handles
    const int ray   = blockIdx.x * RAYS_PER_BLOCK + lane;

    const float* rp = rays + ray * 6;
    const float ox = rp[0], oy = rp[1], oz = rp[2];
    const float dx = rp[3], dy = rp[4], dz = rp[5];

    // a = ((dx*dx)+(dy*dy))+(dz*dz)  -- numpy 3-elem sum order
    const float a     = ((dx*dx) + (dy*dy)) + (dz*dz);
    const float twoA  = 2.0f * a;
    const float fourA = 4.0f * a;
    const float INF   = __builtin_inff();

    float cmin = INF;
    int   carg = 0;       // argmin of all-inf row is 0 (numpy first-occurrence)
    bool  cval = false;

    const int base = chunk * CHUNK;
    for (int s = 0; s < CHUNK; ++s) {
        const int gi = base + s;
        const float fx = ox - cx[gi];
        const float fy = oy - cy[gi];
        const float fz = oz - cz[gi];
        const float b = 2.0f * (((dx*fx) + (dy*fy)) + (dz*fz));
        const float c = (((fx*fx) + (fy*fy)) + (fz*fz)) - r2[gi];
        const float d = (b*b) - (fourA * c);
        const bool valid = d > 0.0f;
        const float ds = valid ? sqrtf(d) : d;   // ds = sqrt(d) if valid else d
        const float nb = -b;
        const float r0 = (nb + ds) / twoA;       // IEEE div, matches numpy
        const float r1 = (nb - ds) / twoA;
        const bool in0 = (r0 >= 1e-8f) && (r0 < 100.0f);
        const bool in1 = (r1 >= 1e-8f) && (r1 < 100.0f);
        const bool mask = valid && (in0 || in1);
        const float rr0 = (r0 < 1e-8f) ? INF : r0;
        const float rr1 = (r1 < 1e-8f) ? INF : r1;
        const float t = mask ? fminf(rr0, rr1) : INF;
        if (t < cmin) { cmin = t; carg = s; }    // strict < => first occurrence
        cval |= mask;
    }

    s_min[chunk][lane] = cmin;
    s_arg[chunk][lane] = carg;
    s_val[chunk][lane] = cval ? 1 : 0;
    __syncthreads();

    if (chunk == 0) {
        float best   = 100.0f;   // T_MAX
        int   face   = -1;
        bool  active = false;
        for (int k = 0; k < NCHUNK; ++k) {
            const float mt = s_min[k][lane];
            const bool  vm = s_val[k][lane] != 0;
            if (vm && (best > mt)) {             // strict >: earlier chunk wins ties
                best = mt;
                face = s_arg[k][lane];           // NOTE: chunk-LOCAL index, as in ref
            }
            active |= vm;
        }

        // p = r_o + best * r_d   (mul then add, no contraction)
        float px = ox + (best * dx);
        float py = oy + (best * dy);
        float pz = oz + (best * dz);

        // idx = clip(face, 0, 1023); face in [-1, 255]
        const int idx = face < 0 ? 0 : face;
        const float ddx = px - cx[idx];
        const float ddy = py - cy[idx];
        const float ddz = pz - cz[idx];
        float nrm = sqrtf(((ddx*ddx) + (ddy*ddy)) + (ddz*ddz));
        nrm = fmaxf(nrm, 1e-12f);
        const float nx = active ? (ddx / nrm) : 0.0f;
        const float ny = active ? (ddy / nrm) : 0.0f;
        const float nz = active ? (ddz / nrm) : 0.0f;
        px = px + (nx * 1e-5f);
        py = py + (ny * 1e-5f);
        pz = pz + (nz * 1e-5f);

        float* outp = out;                 // p: 3*NRAYS floats
        float* outn = out + NRAYS * 3;     // n: 3*NRAYS floats
        float* outd = out + NRAYS * 6;     // best_dists: NRAYS floats
        float* outa = out + NRAYS * 7;     // out_active: NRAYS floats (0/1)

        outp[ray*3 + 0] = px;
        outp[ray*3 + 1] = py;
        outp[ray*3 + 2] = pz;
        outn[ray*3 + 0] = nx;
        outn[ray*3 + 1] = ny;
        outn[ray*3 + 2] = nz;
        outd[ray] = best;
        outa[ray] = active ? 1.0f : 0.0f;
    }
}

extern "C" void kernel_launch(void* const* d_in, const int* in_sizes, int n_in,
                              void* d_out, int out_size, void* d_ws, size_t ws_size,
                              hipStream_t stream) {
    const float* rays    = (const float*)d_in[0];
    const float* centers = (const float*)d_in[1];
    const float* radii   = (const float*)d_in[2];
    float* out = (float*)d_out;

    dim3 grid(NRAYS / RAYS_PER_BLOCK);   // 512 blocks
    dim3 block(256);
    hipLaunchKernelGGL(sphere_kernel, grid, block, 0, stream,
                       rays, centers, radii, out);
}

// Round 2
// 40.747 us; speedup vs baseline: 2.0334x; 2.0334x over previous
//
#include <hip/hip_runtime.h>
#include <math.h>

#define NRAYS 32768      // 16*64*32
#define NSPH  1024
#define SUBS  16         // subchunks per ray
#define SUBSZ 64         // spheres per subchunk
#define RPB   16         // rays per block
#define TPB   256
#define NBLK  (NRAYS / RPB)   // 2048 blocks

__global__ __launch_bounds__(256) void sphere_kernel(
    const float* __restrict__ rays,
    const float* __restrict__ centers,
    const float* __restrict__ radii,
    float* __restrict__ out)
{
#pragma clang fp contract(off)
    // sphere i stored at index i + (i>>6): each 64-sphere group shifted by 16B
    // so the 4 distinct wave broadcast addresses hit disjoint bank quads.
    __shared__ float4 sph[NSPH + NSPH / SUBSZ];   // 1040 * 16B = 16.6 KB
    __shared__ float  s_min[SUBS][RPB];
    __shared__ int    s_pack[SUBS][RPB];

    const int tid = threadIdx.x;

    // Stage all spheres into LDS (SoA float4: cx, cy, cz, r^2).
    for (int i = tid; i < NSPH; i += TPB) {
        const float sx = centers[3 * i + 0];
        const float sy = centers[3 * i + 1];
        const float sz = centers[3 * i + 2];
        const float r  = radii[i];
        sph[i + (i >> 6)] = make_float4(sx, sy, sz, r * r);
    }
    __syncthreads();

    const int rl  = tid & (RPB - 1);   // ray within block, 0..15
    const int sub = tid >> 4;          // subchunk 0..15
    const int ray = blockIdx.x * RPB + rl;

    const float2* rp = (const float2*)(rays + ray * 6);
    const float2 q0 = rp[0], q1 = rp[1], q2 = rp[2];
    const float ox = q0.x, oy = q0.y, oz = q1.x;
    const float dx = q1.y, dy = q2.x, dz = q2.y;

    // a = ((dx*dx)+(dy*dy))+(dz*dz) -- numpy 3-elem sum order
    const float a    = ((dx * dx) + (dy * dy)) + (dz * dz);
    const float epsA = 1e-8f * a;      // w >= epsA  <=>  fl(w/a) >= 1e-8 (up to 1-ulp band)
    const float hunA = 100.0f * a;     // w <  hunA  <=>  fl(w/a) <  100
    const float INF  = __builtin_inff();

    float cw   = INF;   // numerator of current min t
    int   carg = 0;     // argmin within subchunk (first occurrence)
    bool  cval = false;

    const int base = sub * (SUBSZ + 1);   // padded LDS base
    for (int i = 0; i < SUBSZ; ++i) {
        const float4 sp = sph[base + i];
        const float fx = ox - sp.x;
        const float fy = oy - sp.y;
        const float fz = oz - sp.z;
        const float dot = ((dx * fx) + (dy * fy)) + (dz * fz);
        const float c   = (((fx * fx) + (fy * fy)) + (fz * fz)) - sp.w;
        // d = b^2 - 4ac = 4*z with identical rounding (power-of-2 scaling)
        const float z   = (dot * dot) - (a * c);
        const bool valid = z > 0.0f;
        const float s = sqrtf(z);          // ds = 2*s, correctly rounded
        const float w0 = s - dot;          // numerator of r0 = (-b+ds)/2a
        const float w1 = -(dot + s);       // numerator of r1 = (-b-ds)/2a, w1 <= w0
        const bool m1 = (w1 >= epsA) && (w1 < hunA);
        const bool m0 = (w0 >= epsA) && (w0 < hunA);
        const bool mask = valid && (m1 || m0);
        // t numerator: r1 if r1>=eps else r0 (mask guarantees the chosen one <100)
        const float tw = mask ? ((w1 >= epsA) ? w1 : w0) : INF;
        if (tw < cw) { cw = tw; carg = i; }   // strict < => first occurrence
        cval |= mask;
    }

    s_min[sub][rl]  = cw;
    // face is chunk-LOCAL in the 256-sphere reference chunk: ((sub&3)*64 + carg)
    s_pack[sub][rl] = (((sub & 3) << 6) | carg) | (cval ? 0x10000 : 0);
    __syncthreads();

    // Epilogue: threads 0..15 have sub==0, rl==tid -> already hold their ray's data.
    if (tid < RPB) {
        float bw    = INF;
        int   face  = -1;
        bool  active = false;
        for (int k = 0; k < SUBS; ++k) {
            const float mt = s_min[k][tid];
            const int   pk = s_pack[k][tid];
            const bool  vm = (pk & 0x10000) != 0;
            if (vm && (mt < bw)) { bw = mt; face = pk & 0xFFFF; }  // earlier chunk wins ties
            active |= vm;
        }

        // Single IEEE division per ray: best = fl(w*/a) == reference's rounded t.
        const float best = active ? (bw / a) : 100.0f;

        float px = ox + (best * dx);
        float py = oy + (best * dy);
        float pz = oz + (best * dz);

        const int idx = face < 0 ? 0 : face;        // clip(face,0,1023), face in [-1,255]
        const float4 cc = sph[idx + (idx >> 6)];
        const float ddx = px - cc.x;
        const float ddy = py - cc.y;
        const float ddz = pz - cc.z;
        float nrm = sqrtf(((ddx * ddx) + (ddy * ddy)) + (ddz * ddz));
        nrm = fmaxf(nrm, 1e-12f);
        const float nx = active ? (ddx / nrm) : 0.0f;
        const float ny = active ? (ddy / nrm) : 0.0f;
        const float nz = active ? (ddz / nrm) : 0.0f;
        px = px + (nx * 1e-5f);
        py = py + (ny * 1e-5f);
        pz = pz + (nz * 1e-5f);

        const int r = blockIdx.x * RPB + tid;
        float* outp = out;                 // p: 3*NRAYS
        float* outn = out + NRAYS * 3;     // n: 3*NRAYS
        float* outd = out + NRAYS * 6;     // best_dists: NRAYS
        float* outa = out + NRAYS * 7;     // out_active: NRAYS

        outp[r * 3 + 0] = px;
        outp[r * 3 + 1] = py;
        outp[r * 3 + 2] = pz;
        outn[r * 3 + 0] = nx;
        outn[r * 3 + 1] = ny;
        outn[r * 3 + 2] = nz;
        outd[r] = best;
        outa[r] = active ? 1.0f : 0.0f;
    }
}

extern "C" void kernel_launch(void* const* d_in, const int* in_sizes, int n_in,
                              void* d_out, int out_size, void* d_ws, size_t ws_size,
                              hipStream_t stream) {
    const float* rays    = (const float*)d_in[0];
    const float* centers = (const float*)d_in[1];
    const float* radii   = (const float*)d_in[2];
    float* out = (float*)d_out;

    dim3 grid(NBLK);     // 2048 blocks
    dim3 block(TPB);     // 256 threads
    hipLaunchKernelGGL(sphere_kernel, grid, block, 0, stream,
                       rays, centers, radii, out);
}

// Round 3
// 30.722 us; speedup vs baseline: 2.6969x; 1.3263x over previous
//
#include <hip/hip_runtime.h>
#include <math.h>

#define NRAYS 32768      // 16*64*32
#define NSPH  1024
#define SUBS  16         // subchunks per ray
#define SUBSZ 64         // spheres per subchunk
#define RPB   16         // rays per block
#define TPB   256
#define NBLK  (NRAYS / RPB)   // 2048 blocks

__global__ __launch_bounds__(256) void sphere_kernel(
    const float* __restrict__ rays,
    const float* __restrict__ centers,
    const float* __restrict__ radii,
    float* __restrict__ out)
{
#pragma clang fp contract(off)
    // sphere i stored at index i + (i>>6): each 64-sphere group shifted by 16B
    // so the 4 distinct wave broadcast addresses hit disjoint bank quads.
    __shared__ float4 sph[NSPH + NSPH / SUBSZ];   // 1040 * 16B = 16.6 KB
    __shared__ float  s_min[SUBS][RPB];
    __shared__ int    s_face[SUBS][RPB];

    const int tid = threadIdx.x;

    // Stage all spheres into LDS (SoA float4: cx, cy, cz, r^2).
    for (int i = tid; i < NSPH; i += TPB) {
        const float sx = centers[3 * i + 0];
        const float sy = centers[3 * i + 1];
        const float sz = centers[3 * i + 2];
        const float r  = radii[i];
        sph[i + (i >> 6)] = make_float4(sx, sy, sz, r * r);
    }
    __syncthreads();

    const int rl  = tid & (RPB - 1);   // ray within block, 0..15
    const int sub = tid >> 4;          // subchunk 0..15
    const int ray = blockIdx.x * RPB + rl;

    const float2* rp = (const float2*)(rays + ray * 6);
    const float2 q0 = rp[0], q1 = rp[1], q2 = rp[2];
    const float ox = q0.x, oy = q0.y, oz = q1.x;
    const float dx = q1.y, dy = q2.x, dz = q2.y;

    // a = ((dx*dx)+(dy*dy))+(dz*dz) -- numpy 3-elem sum order
    const float a    = ((dx * dx) + (dy * dy)) + (dz * dz);
    const float epsA = 1e-8f * a;      // w >= epsA  <=>  fl(w/a) >= 1e-8 (1-ulp band)
    const float hunA = 100.0f * a;     // w <  hunA  <=>  fl(w/a) <  100
    const float INF  = __builtin_inff();

    float cw   = INF;   // numerator of current min t (w = t*a before rounding)
    int   carg = 0;     // argmin within subchunk (first occurrence)

    const float4* __restrict__ spb = &sph[sub * (SUBSZ + 1)];
#pragma unroll 16
    for (int i = 0; i < SUBSZ; ++i) {
        const float4 sp = spb[i];      // ds_read_b128 with imm offset (unrolled)
        const float fx = ox - sp.x;
        const float fy = oy - sp.y;
        const float fz = oz - sp.z;
        const float dot = ((dx * fx) + (dy * fy)) + (dz * fz);
        const float c   = (((fx * fx) + (fy * fy)) + (fz * fz)) - sp.w;
        // d = b^2 - 4ac = 4*z with identical rounding (power-of-2 scaling)
        const float z   = (dot * dot) - (a * c);
        const float s   = __builtin_amdgcn_sqrtf(z);   // raw v_sqrt; NaN if z<0
        const float w0  = s - dot;         // numerator of r0 = (-b+ds)/2a
        const float w1  = -(dot + s);      // numerator of r1 = (-b-ds)/2a, w1 <= w0
        // min-root numerator: r1 if r1>=eps else r0; window test collapses to u.
        const float u   = (w1 >= epsA) ? w1 : w0;
        const bool  ok  = (z > 0.0f) & (u >= epsA) & (u < hunA);
        const float tw  = ok ? u : INF;
        if (tw < cw) { cw = tw; carg = i; }   // strict < => first occurrence
    }

    s_min[sub][rl]  = cw;
    s_face[sub][rl] = ((sub & 3) << 6) | carg;  // chunk-LOCAL face index (0..255)
    __syncthreads();

    // Epilogue: threads 0..15 handle one ray each.
    if (tid < RPB) {
        float bw   = INF;
        int   face = -1;
        for (int k = 0; k < SUBS; ++k) {
            const float mt = s_min[k][tid];
            if (mt < bw) { bw = mt; face = s_face[k][tid]; }  // earlier subchunk wins ties
        }
        const bool active = bw < INF;   // == any(mask): masked tw always < hunA < INF

        // Single IEEE division per ray: best = fl(w*/a) == reference's rounded t.
        const float best = active ? (bw / a) : 100.0f;

        float px = ox + (best * dx);
        float py = oy + (best * dy);
        float pz = oz + (best * dz);

        const int idx = face < 0 ? 0 : face;        // clip(face,0,1023), face in [-1,255]
        const float4 cc = sph[idx + (idx >> 6)];
        const float ddx = px - cc.x;
        const float ddy = py - cc.y;
        const float ddz = pz - cc.z;
        float nrm = sqrtf(((ddx * ddx) + (ddy * ddy)) + (ddz * ddz));
        nrm = fmaxf(nrm, 1e-12f);
        const float nx = active ? (ddx / nrm) : 0.0f;
        const float ny = active ? (ddy / nrm) : 0.0f;
        const float nz = active ? (ddz / nrm) : 0.0f;
        px = px + (nx * 1e-5f);
        py = py + (ny * 1e-5f);
        pz = pz + (nz * 1e-5f);

        const int r = blockIdx.x * RPB + tid;
        float* outp = out;                 // p: 3*NRAYS
        float* outn = out + NRAYS * 3;     // n: 3*NRAYS
        float* outd = out + NRAYS * 6;     // best_dists: NRAYS
        float* outa = out + NRAYS * 7;     // out_active: NRAYS

        outp[r * 3 + 0] = px;
        outp[r * 3 + 1] = py;
        outp[r * 3 + 2] = pz;
        outn[r * 3 + 0] = nx;
        outn[r * 3 + 1] = ny;
        outn[r * 3 + 2] = nz;
        outd[r] = best;
        outa[r] = active ? 1.0f : 0.0f;
    }
}

extern "C" void kernel_launch(void* const* d_in, const int* in_sizes, int n_in,
                              void* d_out, int out_size, void* d_ws, size_t ws_size,
                              hipStream_t stream) {
    const float* rays    = (const float*)d_in[0];
    const float* centers = (const float*)d_in[1];
    const float* radii   = (const float*)d_in[2];
    float* out = (float*)d_out;

    dim3 grid(NBLK);     // 2048 blocks
    dim3 block(TPB);     // 256 threads
    hipLaunchKernelGGL(sphere_kernel, grid, block, 0, stream,
                       rays, centers, radii, out);
}

// Round 4
// 26.732 us; speedup vs baseline: 3.0994x; 1.1492x over previous
//
#include <hip/hip_runtime.h>
#include <math.h>

#define NRAYS 32768      // 16*64*32
#define NSPH  1024
#define SUBS  16         // subchunks per ray
#define SUBSZ 64         // spheres per subchunk
#define PAIRS 32         // sphere-pairs per subchunk
#define RPB   16         // rays per block
#define TPB   256
#define NBLK  (NRAYS / RPB)   // 2048 blocks

typedef float v2f __attribute__((ext_vector_type(2)));

__global__ __launch_bounds__(256, 8) void sphere_kernel(
    const float* __restrict__ rays,
    const float* __restrict__ centers,
    const float* __restrict__ radii,
    float* __restrict__ out)
{
#pragma clang fp contract(off)
    // Pair-SoA layout: per subchunk of 64 spheres = 32 pairs = 64 float4, +1 pad
    // float4 => subchunk stride 65*16B = 1040B => sub k's broadcast reads land on
    // bank quad 4k (disjoint across the 4 subs of a wave).
    // pair p: sph[base+2p] = (x0,x1,y0,y1), sph[base+2p+1] = (z0,z1,r2_0,r2_1)
    __shared__ float4 sph[SUBS * (2 * PAIRS + 1)];   // 1040 * 16B = 16.6 KB
    __shared__ float  s_min[SUBS][RPB];
    __shared__ int    s_face[SUBS][RPB];

    const int tid = threadIdx.x;

    for (int p = tid; p < NSPH / 2; p += TPB) {
        const int g0 = 2 * p, g1 = 2 * p + 1;
        const float x0 = centers[3 * g0 + 0], y0 = centers[3 * g0 + 1], z0 = centers[3 * g0 + 2];
        const float x1 = centers[3 * g1 + 0], y1 = centers[3 * g1 + 1], z1 = centers[3 * g1 + 2];
        const float r0 = radii[g0], r1 = radii[g1];
        const int b4 = (p >> 5) * (2 * PAIRS + 1) + (p & 31) * 2;
        sph[b4 + 0] = make_float4(x0, x1, y0, y1);
        sph[b4 + 1] = make_float4(z0, z1, r0 * r0, r1 * r1);
    }
    __syncthreads();

    const int rl  = tid & (RPB - 1);   // ray within block, 0..15
    const int sub = tid >> 4;          // subchunk 0..15
    const int ray = blockIdx.x * RPB + rl;

    const float2* rp = (const float2*)(rays + ray * 6);
    const float2 q0 = rp[0], q1 = rp[1], q2 = rp[2];
    const float ox = q0.x, oy = q0.y, oz = q1.x;
    const float dx = q1.y, dy = q2.x, dz = q2.y;

    // a = ((dx*dx)+(dy*dy))+(dz*dz) -- numpy 3-elem sum order
    const float a    = ((dx * dx) + (dy * dy)) + (dz * dz);
    const float epsA = 1e-8f * a;      // w >= epsA  <=>  fl(w/a) >= 1e-8 (1-ulp band)
    const float hunA = 100.0f * a;     // deferred: active <=> bw < hunA
    const float INF  = __builtin_inff();

    const v2f ox2 = {ox, ox}, oy2 = {oy, oy}, oz2 = {oz, oz};
    const v2f dx2 = {dx, dx}, dy2 = {dy, dy}, dz2 = {dz, dz};
    const v2f a2  = {a, a};

    float cw   = INF;   // numerator of current min t (u = t*a before rounding)
    int   carg = 0;     // argmin within subchunk (first occurrence)

    const float4* __restrict__ spb = &sph[sub * (2 * PAIRS + 1)];
#pragma unroll 8
    for (int i = 0; i < PAIRS; ++i) {
        const float4 A = spb[2 * i];       // ds_read_b128
        const float4 B = spb[2 * i + 1];   // ds_read_b128
        const v2f X = {A.x, A.y}, Y = {A.z, A.w};
        const v2f Z = {B.x, B.y}, Q = {B.z, B.w};
        const v2f fx = ox2 - X;
        const v2f fy = oy2 - Y;
        const v2f fz = oz2 - Z;
        const v2f dt = ((dx2 * fx) + (dy2 * fy)) + (dz2 * fz);
        const v2f cc = (((fx * fx) + (fy * fy)) + (fz * fz)) - Q;
        // d = b^2-4ac = 4*z with identical rounding (power-of-2 scaling)
        const v2f zz = (dt * dt) - (a2 * cc);
        const v2f s  = { __builtin_amdgcn_sqrtf(zz.x), __builtin_amdgcn_sqrtf(zz.y) };
        const v2f w0 = s - dt;             // numerator of larger root (NaN if z<0)
        const v2f w1 = -(dt + s);          // numerator of smaller root, w1 <= w0
        {   // sphere 2i
            const float u = (w1.x >= epsA) ? w1.x : w0.x;   // min root >= eps
            const bool upd = (zz.x > 0.0f) & (w0.x >= epsA) & (u < cw);
            cw   = upd ? u : cw;
            carg = upd ? (2 * i) : carg;
        }
        {   // sphere 2i+1
            const float u = (w1.y >= epsA) ? w1.y : w0.y;
            const bool upd = (zz.y > 0.0f) & (w0.y >= epsA) & (u < cw);
            cw   = upd ? u : cw;
            carg = upd ? (2 * i + 1) : carg;
        }
    }

    s_min[sub][rl]  = cw;
    s_face[sub][rl] = ((sub & 3) << 6) | carg;  // chunk-LOCAL face index (0..255)
    __syncthreads();

    // Epilogue: threads 0..15 handle one ray each.
    if (tid < RPB) {
        float bw   = INF;
        int   face = -1;
        for (int k = 0; k < SUBS; ++k) {
            const float mt = s_min[k][tid];
            if (mt < bw) { bw = mt; face = s_face[k][tid]; }  // earlier subchunk wins ties
        }
        // Deferred window test: any in-window u beats every u>=hunA in the min,
        // so bw<hunA <=> reference's any(mask); argmin unaffected.
        const bool active = bw < hunA;

        // Single IEEE division per ray: best = fl(u*/a) == reference's rounded t.
        const float best = active ? (bw / a) : 100.0f;

        float px = ox + (best * dx);
        float py = oy + (best * dy);
        float pz = oz + (best * dz);

        // reference: idx = clip(face,0,1023), face in [-1,255] (chunk-local bug kept)
        const int gidx = (active && face >= 0) ? face : 0;
        const int b4 = (gidx >> 6) * (2 * PAIRS + 1) + ((gidx & 63) >> 1) * 2;
        const int j  = gidx & 1;
        const float4 A = sph[b4];
        const float4 B = sph[b4 + 1];
        const float cxv = j ? A.y : A.x;
        const float cyv = j ? A.w : A.z;
        const float czv = j ? B.y : B.x;
        const float ddx = px - cxv;
        const float ddy = py - cyv;
        const float ddz = pz - czv;
        float nrm = sqrtf(((ddx * ddx) + (ddy * ddy)) + (ddz * ddz));
        nrm = fmaxf(nrm, 1e-12f);
        const float nx = active ? (ddx / nrm) : 0.0f;
        const float ny = active ? (ddy / nrm) : 0.0f;
        const float nz = active ? (ddz / nrm) : 0.0f;
        px = px + (nx * 1e-5f);
        py = py + (ny * 1e-5f);
        pz = pz + (nz * 1e-5f);

        const int r = blockIdx.x * RPB + tid;
        float* outp = out;                 // p: 3*NRAYS
        float* outn = out + NRAYS * 3;     // n: 3*NRAYS
        float* outd = out + NRAYS * 6;     // best_dists: NRAYS
        float* outa = out + NRAYS * 7;     // out_active: NRAYS

        outp[r * 3 + 0] = px;
        outp[r * 3 + 1] = py;
        outp[r * 3 + 2] = pz;
        outn[r * 3 + 0] = nx;
        outn[r * 3 + 1] = ny;
        outn[r * 3 + 2] = nz;
        outd[r] = best;
        outa[r] = active ? 1.0f : 0.0f;
    }
}

extern "C" void kernel_launch(void* const* d_in, const int* in_sizes, int n_in,
                              void* d_out, int out_size, void* d_ws, size_t ws_size,
                              hipStream_t stream) {
    const float* rays    = (const float*)d_in[0];
    const float* centers = (const float*)d_in[1];
    const float* radii   = (const float*)d_in[2];
    float* out = (float*)d_out;

    dim3 grid(NBLK);     // 2048 blocks
    dim3 block(TPB);     // 256 threads
    hipLaunchKernelGGL(sphere_kernel, grid, block, 0, stream,
                       rays, centers, radii, out);
}